// Round 5
// baseline (808.310 us; speedup 1.0000x reference)
//
#include <hip/hip_runtime.h>

#define SEQ   2048
#define HD    128
#define BN    64
#define NITER (SEQ / BN)

typedef __fp16 f16x2 __attribute__((ext_vector_type(2)));
typedef __fp16 f16x4 __attribute__((ext_vector_type(4)));
typedef __fp16 f16x8 __attribute__((ext_vector_type(8)));
typedef float  f32x4 __attribute__((ext_vector_type(4)));

// pack two fp32 -> one uint of two f16 (RTZ)
__device__ __forceinline__ unsigned pkh(float a, float b) {
  auto h = __builtin_amdgcn_cvt_pkrtz(a, b);
  return __builtin_bit_cast(unsigned, h);
}

__global__ __launch_bounds__(256, 3)
void fa_gqa_kernel(const float* __restrict__ Q,
                   const float* __restrict__ K,
                   const float* __restrict__ V,
                   float* __restrict__ O)
{
  // K tile [64 k][128 d] f16; 16B chunk j at position j ^ (row&15)
  __shared__ unsigned short kt_lds[64 * HD];
  // V^T tile [128 d][64 k] f16; b64 granule g=k>>2 at pos g ^ (d&15) ^ (d>>4)
  __shared__ unsigned short vt_lds[HD * 64];

  const int tid  = threadIdx.x;
  const int lane = tid & 63;
  const int w    = tid >> 6;
  const int c    = lane & 15;   // MFMA col lane index
  const int qh   = lane >> 4;   // quad

  // XCD-clustered virtual block mapping (K/V L2 locality)
  const int F     = blockIdx.x;        // 0..1023
  const int xcd   = F & 7;
  const int s     = F >> 3;
  const int bh    = xcd * 8 + (s >> 4);
  const int qtile = s & 15;

  const int b = bh >> 5;
  const int h = bh & 31;
  const long qrow0 = (long)bh * SEQ + qtile * 128 + w * 32;
  const float* Qw = Q + qrow0 * HD;
  float*       Ow = O + qrow0 * HD;
  const long kvoff = (long)(b * 8 + (h >> 2)) * SEQ * HD;
  const float* Kb = K + kvoff;
  const float* Vb = V + kvoff;

  // Q fragments (B-operand of 16x16x32: lane (c,qh) holds Q[q=qt*16+c][d=dc*32+qh*8+j])
  f16x8 qf[2][4];
#pragma unroll
  for (int qt = 0; qt < 2; ++qt)
#pragma unroll
    for (int dc = 0; dc < 4; ++dc) {
      const float4* qp = (const float4*)(Qw + (qt * 16 + c) * HD + dc * 32 + qh * 8);
      float4 a = qp[0], bq = qp[1];
      int4 t;
      t.x = (int)pkh(a.x, a.y);
      t.y = (int)pkh(a.z, a.w);
      t.z = (int)pkh(bq.x, bq.y);
      t.w = (int)pkh(bq.z, bq.w);
      qf[qt][dc] = __builtin_bit_cast(f16x8, t);
    }

  // O^T accumulator: oacc[mt][dt], lane holds O[q=mt*16+c][d=dt*16+qh*4+r]
  f32x4 oacc[2][8];
#pragma unroll
  for (int mt = 0; mt < 2; ++mt)
#pragma unroll
    for (int dt = 0; dt < 8; ++dt)
      oacc[mt][dt] = (f32x4){0.f, 0.f, 0.f, 0.f};

  float mst[2] = {-1e30f, -1e30f};
  float lst[2] = {0.f, 0.f};

  const float K1 = 0.08838834764831845f * 1.4426950408889634f; // scale*log2(e)

  // staging roles
  const int krow = tid >> 2;      // K: 0..63
  const int kq4  = tid & 3;       // K: 32-float quarter of the row
  const int kq   = tid >> 4;      // V: k-quad 0..15 (rows 4kq..4kq+3)
  const int dc8  = tid & 15;      // V: 8-float d chunk

  for (int it = 0; it < NITER; ++it) {
    const int k0 = it * BN;

    // ---- global loads + cvt to f16 (pre-barrier; halves live regs) ----
    const float* kp = Kb + (long)(k0 + krow) * HD + kq4 * 32;
    int4 ks[4];
#pragma unroll
    for (int jj = 0; jj < 4; ++jj) {
      float4 e = ((const float4*)kp)[2 * jj];
      float4 o = ((const float4*)kp)[2 * jj + 1];
      ks[jj].x = (int)pkh(e.x, e.y);
      ks[jj].y = (int)pkh(e.z, e.w);
      ks[jj].z = (int)pkh(o.x, o.y);
      ks[jj].w = (int)pkh(o.z, o.w);
    }

    const float* vp = Vb + (long)(k0 + 4 * kq) * HD + dc8 * 8;
    float4 vr[4][2];
#pragma unroll
    for (int r = 0; r < 4; ++r) {
      vr[r][0] = ((const float4*)(vp + r * HD))[0];
      vr[r][1] = ((const float4*)(vp + r * HD))[1];
    }
    uint2 vs[8];
#pragma unroll
    for (int jd = 0; jd < 8; ++jd) {
      const int hsel = jd >> 2, e = jd & 3;
      float x0 = ((const float*)&vr[0][hsel])[e];
      float x1 = ((const float*)&vr[1][hsel])[e];
      float x2 = ((const float*)&vr[2][hsel])[e];
      float x3 = ((const float*)&vr[3][hsel])[e];
      vs[jd].x = pkh(x0, x1);
      vs[jd].y = pkh(x2, x3);
    }

    __syncthreads();  // (A) all waves done reading prev tiles

    // K staging: 4 swizzled b128 stores
#pragma unroll
    for (int jj = 0; jj < 4; ++jj) {
      int j = kq4 * 4 + jj;
      int pos = j ^ (krow & 15);
      *(int4*)(kt_lds + krow * HD + pos * 8) = ks[jj];
    }
    // V^T staging: 8 swizzled b64 stores (conflict-free per phase)
#pragma unroll
    for (int jd = 0; jd < 8; ++jd) {
      int d = dc8 * 8 + jd;
      int pos = kq ^ (d & 15) ^ (d >> 4);
      *(uint2*)(vt_lds + d * 64 + pos * 4) = vs[jd];
    }

    __syncthreads();  // (B) staging visible

    // ---- S^T = K * Q^T (16x16x32): lane holds S[q=qt*16+c][k=kt*16+qh*4+r] ----
    f32x4 sacc[4][2];
#pragma unroll
    for (int kt = 0; kt < 4; ++kt)
#pragma unroll
      for (int qt = 0; qt < 2; ++qt)
        sacc[kt][qt] = (f32x4){0.f, 0.f, 0.f, 0.f};

#pragma unroll
    for (int dc = 0; dc < 4; ++dc) {
#pragma unroll
      for (int kt = 0; kt < 4; ++kt) {
        int row = kt * 16 + c;
        int pos = (4 * dc + qh) ^ c;
        f16x8 af = *(const f16x8*)(kt_lds + row * HD + pos * 8);
#pragma unroll
        for (int qt = 0; qt < 2; ++qt)
          sacc[kt][qt] = __builtin_amdgcn_mfma_f32_16x16x32_f16(
              af, qf[qt][dc], sacc[kt][qt], 0, 0, 0);
      }
    }

    // ---- online softmax per q=c column ----
    float alpha[2];
#pragma unroll
    for (int qt = 0; qt < 2; ++qt) {
      float mx = sacc[0][qt][0];
#pragma unroll
      for (int kt = 0; kt < 4; ++kt)
#pragma unroll
        for (int r = 0; r < 4; ++r)
          mx = fmaxf(mx, sacc[kt][qt][r]);
      mx = fmaxf(mx, __shfl_xor(mx, 16, 64));
      mx = fmaxf(mx, __shfl_xor(mx, 32, 64));
      float mnew = fmaxf(mst[qt], mx);
      alpha[qt] = __builtin_amdgcn_exp2f(K1 * (mst[qt] - mnew));
      mst[qt] = mnew;
      float nm = -K1 * mnew;
      float sum = 0.f;
#pragma unroll
      for (int kt = 0; kt < 4; ++kt)
#pragma unroll
        for (int r = 0; r < 4; ++r) {
          float p = __builtin_amdgcn_exp2f(fmaf(sacc[kt][qt][r], K1, nm));
          sacc[kt][qt][r] = p;
          sum += p;
        }
      lst[qt] = lst[qt] * alpha[qt] + sum;  // quad-partial l
    }

    // P fragments (f16) straight from sacc: B-operand of 16x16x16 (k=qh*4+j)
    f16x4 pf[4][2];
#pragma unroll
    for (int kt = 0; kt < 4; ++kt)
#pragma unroll
      for (int qt = 0; qt < 2; ++qt) {
        uint2 u;
        u.x = pkh(sacc[kt][qt][0], sacc[kt][qt][1]);
        u.y = pkh(sacc[kt][qt][2], sacc[kt][qt][3]);
        pf[kt][qt] = __builtin_bit_cast(f16x4, u);
      }

    // rescale O^T by alpha (direct: lane's q = c for both layouts)
#pragma unroll
    for (int mt = 0; mt < 2; ++mt)
#pragma unroll
      for (int dt = 0; dt < 8; ++dt)
        oacc[mt][dt] *= alpha[mt];

    // ---- O^T += V^T * P^T (16x16x16): A=V^T frag (b64 LDS), B=P regs ----
#pragma unroll
    for (int kt = 0; kt < 4; ++kt) {
#pragma unroll
      for (int dt = 0; dt < 8; ++dt) {
        int pos = (4 * kt + qh) ^ c ^ dt;
        f16x4 vf = *(const f16x4*)(vt_lds + (dt * 16 + c) * 64 + pos * 4);
#pragma unroll
        for (int qt = 0; qt < 2; ++qt)
          oacc[qt][dt] = __builtin_amdgcn_mfma_f32_16x16x16f16(
              vf, pf[kt][qt], oacc[qt][dt], 0, 0, 0);
      }
    }
  }

  // ---- epilogue: finish l across quads, normalize, vectorized store ----
  float linv[2];
#pragma unroll
  for (int qt = 0; qt < 2; ++qt) {
    float lf = lst[qt];
    lf += __shfl_xor(lf, 16, 64);
    lf += __shfl_xor(lf, 32, 64);
    linv[qt] = 1.0f / lf;
  }
#pragma unroll
  for (int mt = 0; mt < 2; ++mt) {
#pragma unroll
    for (int dt = 0; dt < 8; ++dt) {
      f32x4 ov = oacc[mt][dt] * linv[mt];
      *(f32x4*)(Ow + (mt * 16 + c) * HD + dt * 16 + qh * 4) = ov;
    }
  }
}

extern "C" void kernel_launch(void* const* d_in, const int* in_sizes, int n_in,
                              void* d_out, int out_size, void* d_ws, size_t ws_size,
                              hipStream_t stream) {
  const float* q = (const float*)d_in[0];
  const float* k = (const float*)d_in[1];
  const float* v = (const float*)d_in[2];
  float* o = (float*)d_out;
  fa_gqa_kernel<<<dim3(1024), dim3(256), 0, stream>>>(q, k, v, o);
}

// Round 6
// 336.097 us; speedup vs baseline: 2.4050x; 2.4050x over previous
//
#include <hip/hip_runtime.h>

#define SEQ   2048
#define HD    128
#define BN    64
#define NITER (SEQ / BN)

typedef __fp16 f16x2 __attribute__((ext_vector_type(2)));
typedef __fp16 f16x4 __attribute__((ext_vector_type(4)));
typedef __fp16 f16x8 __attribute__((ext_vector_type(8)));
typedef float  f32x4 __attribute__((ext_vector_type(4)));

// pack two fp32 -> one uint of two f16 (RTZ)
__device__ __forceinline__ unsigned pkh(float a, float b) {
  auto h = __builtin_amdgcn_cvt_pkrtz(a, b);
  return __builtin_bit_cast(unsigned, h);
}

__global__ __launch_bounds__(256, 2)
void fa_gqa_kernel(const float* __restrict__ Q,
                   const float* __restrict__ K,
                   const float* __restrict__ V,
                   float* __restrict__ O)
{
  // K tile [64 k][128 d] f16; 16B chunk j at position j ^ (row&15)
  __shared__ unsigned short kt_lds[64 * HD];
  // V^T tile [128 d][64 k] f16; b64 granule g=k>>2 at pos g ^ (d&15) ^ (d>>4)
  __shared__ unsigned short vt_lds[HD * 64];

  const int tid  = threadIdx.x;
  const int lane = tid & 63;
  const int w    = tid >> 6;
  const int c    = lane & 15;   // MFMA col lane index
  const int qh   = lane >> 4;   // quad

  // XCD-clustered virtual block mapping (K/V L2 locality)
  const int F     = blockIdx.x;        // 0..1023
  const int xcd   = F & 7;
  const int s     = F >> 3;
  const int bh    = xcd * 8 + (s >> 4);
  const int qtile = s & 15;

  const int b = bh >> 5;
  const int h = bh & 31;
  const long qrow0 = (long)bh * SEQ + qtile * 128 + w * 32;
  const float* Qw = Q + qrow0 * HD;
  float*       Ow = O + qrow0 * HD;
  const long kvoff = (long)(b * 8 + (h >> 2)) * SEQ * HD;
  const float* Kb = K + kvoff;
  const float* Vb = V + kvoff;

  // Q fragments (B-operand of 16x16x32: lane (c,qh) holds Q[q=qt*16+c][d=dc*32+qh*8+j])
  f16x8 qf[2][4];
#pragma unroll
  for (int qt = 0; qt < 2; ++qt)
#pragma unroll
    for (int dc = 0; dc < 4; ++dc) {
      const float4* qp = (const float4*)(Qw + (qt * 16 + c) * HD + dc * 32 + qh * 8);
      float4 a = qp[0], bq = qp[1];
      int4 t;
      t.x = (int)pkh(a.x, a.y);
      t.y = (int)pkh(a.z, a.w);
      t.z = (int)pkh(bq.x, bq.y);
      t.w = (int)pkh(bq.z, bq.w);
      qf[qt][dc] = __builtin_bit_cast(f16x8, t);
    }

  // O^T accumulator: oacc[mt][dt], lane holds O[q=mt*16+c][d=dt*16+qh*4+r]
  f32x4 oacc[2][8];
#pragma unroll
  for (int mt = 0; mt < 2; ++mt)
#pragma unroll
    for (int dt = 0; dt < 8; ++dt)
      oacc[mt][dt] = (f32x4){0.f, 0.f, 0.f, 0.f};

  float mst[2] = {-1e30f, -1e30f};
  float lst[2] = {0.f, 0.f};

  const float K1 = 0.08838834764831845f * 1.4426950408889634f; // scale*log2(e)

  // staging roles
  const int krow = tid >> 2;      // K: 0..63
  const int kq4  = tid & 3;       // K: 32-float quarter of the row
  const int kq   = tid >> 4;      // V: k-quad 0..15 (rows 4kq..4kq+3)
  const int dc8  = tid & 15;      // V: 8-float d chunk

  for (int it = 0; it < NITER; ++it) {
    const int k0 = it * BN;

    // ---- global loads + cvt to f16 (pre-barrier; halves live regs) ----
    const float* kp = Kb + (long)(k0 + krow) * HD + kq4 * 32;
    int4 ks[4];
#pragma unroll
    for (int jj = 0; jj < 4; ++jj) {
      float4 e = ((const float4*)kp)[2 * jj];
      float4 o = ((const float4*)kp)[2 * jj + 1];
      ks[jj].x = (int)pkh(e.x, e.y);
      ks[jj].y = (int)pkh(e.z, e.w);
      ks[jj].z = (int)pkh(o.x, o.y);
      ks[jj].w = (int)pkh(o.z, o.w);
    }

    const float* vp = Vb + (long)(k0 + 4 * kq) * HD + dc8 * 8;
    float4 vr[4][2];
#pragma unroll
    for (int r = 0; r < 4; ++r) {
      vr[r][0] = ((const float4*)(vp + r * HD))[0];
      vr[r][1] = ((const float4*)(vp + r * HD))[1];
    }
    uint2 vs[8];
#pragma unroll
    for (int jd = 0; jd < 8; ++jd) {
      const int hsel = jd >> 2, e = jd & 3;
      float x0 = ((const float*)&vr[0][hsel])[e];
      float x1 = ((const float*)&vr[1][hsel])[e];
      float x2 = ((const float*)&vr[2][hsel])[e];
      float x3 = ((const float*)&vr[3][hsel])[e];
      vs[jd].x = pkh(x0, x1);
      vs[jd].y = pkh(x2, x3);
    }

    __syncthreads();  // (A) all waves done reading prev tiles

    // K staging: 4 swizzled b128 stores
#pragma unroll
    for (int jj = 0; jj < 4; ++jj) {
      int j = kq4 * 4 + jj;
      int pos = j ^ (krow & 15);
      *(int4*)(kt_lds + krow * HD + pos * 8) = ks[jj];
    }
    // V^T staging: 8 swizzled b64 stores (conflict-free per phase)
#pragma unroll
    for (int jd = 0; jd < 8; ++jd) {
      int d = dc8 * 8 + jd;
      int pos = kq ^ (d & 15) ^ (d >> 4);
      *(uint2*)(vt_lds + d * 64 + pos * 4) = vs[jd];
    }

    __syncthreads();  // (B) staging visible

    // ---- S^T = K * Q^T (16x16x32): lane holds S[q=qt*16+c][k=kt*16+qh*4+r] ----
    f32x4 sacc[4][2];
#pragma unroll
    for (int kt = 0; kt < 4; ++kt)
#pragma unroll
      for (int qt = 0; qt < 2; ++qt)
        sacc[kt][qt] = (f32x4){0.f, 0.f, 0.f, 0.f};

#pragma unroll
    for (int dc = 0; dc < 4; ++dc) {
#pragma unroll
      for (int kt = 0; kt < 4; ++kt) {
        int row = kt * 16 + c;
        int pos = (4 * dc + qh) ^ c;
        f16x8 af = *(const f16x8*)(kt_lds + row * HD + pos * 8);
#pragma unroll
        for (int qt = 0; qt < 2; ++qt)
          sacc[kt][qt] = __builtin_amdgcn_mfma_f32_16x16x32_f16(
              af, qf[qt][dc], sacc[kt][qt], 0, 0, 0);
      }
    }

    // ---- online softmax per q=c column ----
    float alpha[2];
#pragma unroll
    for (int qt = 0; qt < 2; ++qt) {
      float mx = sacc[0][qt][0];
#pragma unroll
      for (int kt = 0; kt < 4; ++kt)
#pragma unroll
        for (int r = 0; r < 4; ++r)
          mx = fmaxf(mx, sacc[kt][qt][r]);
      mx = fmaxf(mx, __shfl_xor(mx, 16, 64));
      mx = fmaxf(mx, __shfl_xor(mx, 32, 64));
      float mnew = fmaxf(mst[qt], mx);
      alpha[qt] = __builtin_amdgcn_exp2f(K1 * (mst[qt] - mnew));
      mst[qt] = mnew;
      float nm = -K1 * mnew;
      float sum = 0.f;
#pragma unroll
      for (int kt = 0; kt < 4; ++kt)
#pragma unroll
        for (int r = 0; r < 4; ++r) {
          float p = __builtin_amdgcn_exp2f(fmaf(sacc[kt][qt][r], K1, nm));
          sacc[kt][qt][r] = p;
          sum += p;
        }
      lst[qt] = lst[qt] * alpha[qt] + sum;  // quad-partial l
    }

    // P fragments (f16) straight from sacc: B-operand of 16x16x16 (k=qh*4+j)
    f16x4 pf[4][2];
#pragma unroll
    for (int kt = 0; kt < 4; ++kt)
#pragma unroll
      for (int qt = 0; qt < 2; ++qt) {
        uint2 u;
        u.x = pkh(sacc[kt][qt][0], sacc[kt][qt][1]);
        u.y = pkh(sacc[kt][qt][2], sacc[kt][qt][3]);
        pf[kt][qt] = __builtin_bit_cast(f16x4, u);
      }

    // rescale O^T by alpha (direct: lane's q = c for both layouts)
#pragma unroll
    for (int mt = 0; mt < 2; ++mt)
#pragma unroll
      for (int dt = 0; dt < 8; ++dt)
        oacc[mt][dt] *= alpha[mt];

    // ---- O^T += V^T * P^T (16x16x16): A=V^T frag (b64 LDS), B=P regs ----
#pragma unroll
    for (int kt = 0; kt < 4; ++kt) {
#pragma unroll
      for (int dt = 0; dt < 8; ++dt) {
        int pos = (4 * kt + qh) ^ c ^ dt;
        f16x4 vf = *(const f16x4*)(vt_lds + (dt * 16 + c) * 64 + pos * 4);
#pragma unroll
        for (int qt = 0; qt < 2; ++qt)
          oacc[qt][dt] = __builtin_amdgcn_mfma_f32_16x16x16f16(
              vf, pf[kt][qt], oacc[qt][dt], 0, 0, 0);
      }
    }
  }

  // ---- epilogue: finish l across quads, normalize, vectorized store ----
  float linv[2];
#pragma unroll
  for (int qt = 0; qt < 2; ++qt) {
    float lf = lst[qt];
    lf += __shfl_xor(lf, 16, 64);
    lf += __shfl_xor(lf, 32, 64);
    linv[qt] = 1.0f / lf;
  }
#pragma unroll
  for (int mt = 0; mt < 2; ++mt) {
#pragma unroll
    for (int dt = 0; dt < 8; ++dt) {
      f32x4 ov = oacc[mt][dt] * linv[mt];
      *(f32x4*)(Ow + (mt * 16 + c) * HD + dt * 16 + qh * 4) = ov;
    }
  }
}

extern "C" void kernel_launch(void* const* d_in, const int* in_sizes, int n_in,
                              void* d_out, int out_size, void* d_ws, size_t ws_size,
                              hipStream_t stream) {
  const float* q = (const float*)d_in[0];
  const float* k = (const float*)d_in[1];
  const float* v = (const float*)d_in[2];
  float* o = (float*)d_out;
  fa_gqa_kernel<<<dim3(1024), dim3(256), 0, stream>>>(q, k, v, o);
}

// Round 7
// 321.580 us; speedup vs baseline: 2.5136x; 1.0451x over previous
//
#include <hip/hip_runtime.h>

#define SEQ   2048
#define HD    128
#define BN    64
#define NITER (SEQ / BN)

typedef __fp16 f16x8  __attribute__((ext_vector_type(8)));
typedef float  f32x4  __attribute__((ext_vector_type(4)));
typedef float  f32x16 __attribute__((ext_vector_type(16)));

// pack two fp32 -> one uint of two f16 (RTZ)
__device__ __forceinline__ unsigned pkh(float a, float b) {
  auto h = __builtin_amdgcn_cvt_pkrtz(a, b);
  return __builtin_bit_cast(unsigned, h);
}

__global__ __launch_bounds__(256, 2)
void fa_gqa_kernel(const float* __restrict__ Q,
                   const float* __restrict__ K,
                   const float* __restrict__ V,
                   float* __restrict__ O)
{
  // K tile [64 k][128 d] f16; 16B chunk j at position j ^ (row&15)
  __shared__ unsigned short kt_lds[64 * HD];
  // V^T tile [128 d][64 k] f16; 16B chunk c8 (8 k) at pos c8 ^ (((d>>3)^d)&7)
  __shared__ unsigned short vt_lds[HD * 64];

  const int tid  = threadIdx.x;
  const int lane = tid & 63;
  const int w    = tid >> 6;
  const int ml   = lane & 31;   // 32x32 MFMA row/col lane index
  const int hi   = lane >> 5;   // half-wave select
  const bool hib = (hi != 0);

  // XCD-clustered virtual block mapping (K/V L2 locality)
  const int F     = blockIdx.x;        // 0..1023
  const int xcd   = F & 7;
  const int s     = F >> 3;
  const int bh    = xcd * 8 + (s >> 4);
  const int qtile = s & 15;

  const int b = bh >> 5;
  const int h = bh & 31;
  const long qrow0 = (long)bh * SEQ + qtile * 128 + w * 32;
  const float* Qw = Q + qrow0 * HD;
  float*       Ow = O + qrow0 * HD;
  const long kvoff = (long)(b * 8 + (h >> 2)) * SEQ * HD;
  const float* Kb = K + kvoff;
  const float* Vb = V + kvoff;

  // Q fragments (B-operand of 32x32x16: lane holds Q[q=w*32+ml][d=dc*16+hi*8+j])
  f16x8 qf[8];
#pragma unroll
  for (int dc = 0; dc < 8; ++dc) {
    const float4* qp = (const float4*)(Qw + ml * HD + dc * 16 + hi * 8);
    float4 a = qp[0], bq = qp[1];
    int4 t;
    t.x = (int)pkh(a.x, a.y);
    t.y = (int)pkh(a.z, a.w);
    t.z = (int)pkh(bq.x, bq.y);
    t.w = (int)pkh(bq.z, bq.w);
    qf[dc] = __builtin_bit_cast(f16x8, t);
  }

  // O^T accumulators: 4 d-tiles of 32x32; lane holds O[q=ml][d=dt*32+(r&3)+8(r>>2)+4hi]
  f32x16 oacc[4];
#pragma unroll
  for (int dt = 0; dt < 4; ++dt)
    oacc[dt] = (f32x16)(0.f);

  float mst = -1e30f;
  float lst = 0.f;

  const float K1 = 0.08838834764831845f * 1.4426950408889634f; // scale*log2(e)

  // staging roles
  const int krow = tid >> 2;      // K: 0..63
  const int kq4  = tid & 3;       // K: 32-float quarter of the row
  const int kq   = tid >> 4;      // V: k-quad 0..15 (rows 4kq..4kq+3)
  const int dc8  = tid & 15;      // V: 8-float d chunk

  for (int it = 0; it < NITER; ++it) {
    const int k0 = it * BN;

    // ---- global loads + cvt to f16 (pre-barrier) ----
    const float* kp = Kb + (long)(k0 + krow) * HD + kq4 * 32;
    int4 ks[4];
#pragma unroll
    for (int jj = 0; jj < 4; ++jj) {
      float4 e = ((const float4*)kp)[2 * jj];
      float4 o = ((const float4*)kp)[2 * jj + 1];
      ks[jj].x = (int)pkh(e.x, e.y);
      ks[jj].y = (int)pkh(e.z, e.w);
      ks[jj].z = (int)pkh(o.x, o.y);
      ks[jj].w = (int)pkh(o.z, o.w);
    }

    const float* vp = Vb + (long)(k0 + 4 * kq) * HD + dc8 * 8;
    float4 vr[4][2];
#pragma unroll
    for (int r = 0; r < 4; ++r) {
      vr[r][0] = ((const float4*)(vp + r * HD))[0];
      vr[r][1] = ((const float4*)(vp + r * HD))[1];
    }
    uint2 vs[8];
#pragma unroll
    for (int jd = 0; jd < 8; ++jd) {
      const int hsel = jd >> 2, e = jd & 3;
      float x0 = ((const float*)&vr[0][hsel])[e];
      float x1 = ((const float*)&vr[1][hsel])[e];
      float x2 = ((const float*)&vr[2][hsel])[e];
      float x3 = ((const float*)&vr[3][hsel])[e];
      vs[jd].x = pkh(x0, x1);
      vs[jd].y = pkh(x2, x3);
    }

    __syncthreads();  // (A) all waves done reading prev tiles

    // K staging: 4 swizzled b128 stores
#pragma unroll
    for (int jj = 0; jj < 4; ++jj) {
      int j = kq4 * 4 + jj;
      int pos = j ^ (krow & 15);
      *(int4*)(kt_lds + krow * HD + pos * 8) = ks[jj];
    }
    // V^T staging: 8 swizzled b64 stores; 16B chunk (kq>>1) at pos ^ sw3(d)
#pragma unroll
    for (int jd = 0; jd < 8; ++jd) {
      int d = dc8 * 8 + jd;
      int sw3 = ((d >> 3) ^ d) & 7;
      int pos = (kq >> 1) ^ sw3;
      *(uint2*)(vt_lds + d * 64 + pos * 8 + (kq & 1) * 4) = vs[jd];
    }

    __syncthreads();  // (B) staging visible

    // ---- S^T = K * Q^T (32x32x16): lane holds S[q=ml][k=kt*32+(r&3)+8(r>>2)+4hi] ----
    f32x16 sacc[2];
    sacc[0] = (f32x16)(0.f);
    sacc[1] = (f32x16)(0.f);

#pragma unroll
    for (int dc = 0; dc < 8; ++dc) {
#pragma unroll
      for (int kt = 0; kt < 2; ++kt) {
        int row = kt * 32 + ml;
        int pos = (2 * dc + hi) ^ (row & 15);
        f16x8 af = *(const f16x8*)(kt_lds + row * HD + pos * 8);
        sacc[kt] = __builtin_amdgcn_mfma_f32_32x32x16_f16(
            af, qf[dc], sacc[kt], 0, 0, 0);
      }
    }

    // ---- online softmax: one q-column per lane ----
    float mx = sacc[0][0];
#pragma unroll
    for (int kt = 0; kt < 2; ++kt)
#pragma unroll
      for (int r = 0; r < 16; ++r)
        mx = fmaxf(mx, sacc[kt][r]);
    mx = fmaxf(mx, __shfl_xor(mx, 32, 64));
    float mnew = fmaxf(mst, mx);
    float alpha = __builtin_amdgcn_exp2f(K1 * (mst - mnew));
    mst = mnew;
    float nm = -K1 * mnew;
    float sum = 0.f;
#pragma unroll
    for (int kt = 0; kt < 2; ++kt)
#pragma unroll
      for (int r = 0; r < 16; ++r) {
        float p = __builtin_amdgcn_exp2f(fmaf(sacc[kt][r], K1, nm));
        sacc[kt][r] = p;
        sum += p;
      }
    lst = lst * alpha + sum;  // half-lane-partial l (reduced at epilogue)

    // rescale O^T (lane's q = ml, uniform across regs)
#pragma unroll
    for (int dt = 0; dt < 4; ++dt)
      oacc[dt] *= alpha;

    // ---- O^T += V^T * P^T (32x32x16), 4 k-steps of 16 ----
#pragma unroll
    for (int st = 0; st < 4; ++st) {
      const int kt = st >> 1;
      const int R  = 8 * (st & 1);
      // assemble B-frag: lane (q=ml,hi) needs k = st*16 + hi*8 + (0..7)
      unsigned pA0 = pkh(sacc[kt][R + 0], sacc[kt][R + 1]);
      unsigned pA1 = pkh(sacc[kt][R + 2], sacc[kt][R + 3]);
      unsigned pB0 = pkh(sacc[kt][R + 4], sacc[kt][R + 5]);
      unsigned pB1 = pkh(sacc[kt][R + 6], sacc[kt][R + 7]);
      unsigned s0 = hib ? pA0 : pB0;
      unsigned s1 = hib ? pA1 : pB1;
      unsigned r0 = (unsigned)__shfl_xor((int)s0, 32, 64);
      unsigned r1 = (unsigned)__shfl_xor((int)s1, 32, 64);
      int4 bf;
      bf.x = (int)(hib ? r0 : pA0);
      bf.y = (int)(hib ? r1 : pA1);
      bf.z = (int)(hib ? pB0 : r0);
      bf.w = (int)(hib ? pB1 : r1);
      f16x8 pfrag = __builtin_bit_cast(f16x8, bf);
#pragma unroll
      for (int dt = 0; dt < 4; ++dt) {
        int d = dt * 32 + ml;
        int pos = (2 * st + hi) ^ (((d >> 3) ^ d) & 7);
        f16x8 vf = *(const f16x8*)(vt_lds + d * 64 + pos * 8);
        oacc[dt] = __builtin_amdgcn_mfma_f32_32x32x16_f16(
            vf, pfrag, oacc[dt], 0, 0, 0);
      }
    }
  }

  // ---- epilogue: finish l across half-waves, normalize, float4 stores ----
  float lf = lst + __shfl_xor(lst, 32, 64);
  float linv = 1.0f / lf;
#pragma unroll
  for (int dt = 0; dt < 4; ++dt) {
#pragma unroll
    for (int t = 0; t < 4; ++t) {
      f32x4 ov;
      ov[0] = oacc[dt][4 * t + 0] * linv;
      ov[1] = oacc[dt][4 * t + 1] * linv;
      ov[2] = oacc[dt][4 * t + 2] * linv;
      ov[3] = oacc[dt][4 * t + 3] * linv;
      *(f32x4*)(Ow + ml * HD + dt * 32 + 8 * t + 4 * hi) = ov;
    }
  }
}

extern "C" void kernel_launch(void* const* d_in, const int* in_sizes, int n_in,
                              void* d_out, int out_size, void* d_ws, size_t ws_size,
                              hipStream_t stream) {
  const float* q = (const float*)d_in[0];
  const float* k = (const float*)d_in[1];
  const float* v = (const float*)d_in[2];
  float* o = (float*)d_out;
  fa_gqa_kernel<<<dim3(1024), dim3(256), 0, stream>>>(q, k, v, o);
}